// Round 5
// baseline (542.720 us; speedup 1.0000x reference)
//
#include <hip/hip_runtime.h>

#define NN 100000
#define NE 200000
#define MT (NN + NE)

typedef unsigned short u16;
typedef __attribute__((ext_vector_type(8))) short bf16x8;
typedef __attribute__((ext_vector_type(4))) float f32x4;

__device__ __forceinline__ float bf2f(u16 u) {
    union { unsigned int i; float f; } v; v.i = ((unsigned int)u) << 16; return v.f;
}
__device__ __forceinline__ u16 f2bf(float f) {
    union { unsigned int i; float f; } v; v.f = f;
    unsigned int r = v.i + 0x7fffu + ((v.i >> 16) & 1u);
    return (u16)(r >> 16);
}
__device__ __forceinline__ void unpack2(unsigned int u, float& lo, float& hi) {
    union { unsigned int i; float f; } a, b;
    a.i = u << 16; b.i = u & 0xffff0000u;
    lo = a.f; hi = b.f;
}
__device__ __forceinline__ unsigned int pack2(float a, float b) {
    return (unsigned int)f2bf(a) | ((unsigned int)f2bf(b) << 16);
}
// Dtype-flexible scalar load (R2-R4 proven): f32 flag ? float : bf16.
__device__ __forceinline__ float loadf(const void* p, size_t i, int f32) {
    return f32 ? ((const float*)p)[i] : bf2f(((const u16*)p)[i]);
}
__device__ __forceinline__ void acc8(float a[8], uint4 g) {
    float e0, e1, e2, e3, e4, e5, e6, e7;
    unpack2(g.x, e0, e1); unpack2(g.y, e2, e3);
    unpack2(g.z, e4, e5); unpack2(g.w, e6, e7);
    a[0] += e0; a[1] += e1; a[2] += e2; a[3] += e3;
    a[4] += e4; a[5] += e5; a[6] += e6; a[7] += e7;
}

// Detect input dtype from bit patterns of x (R2-R4 proven). flag=1 => fp32.
__global__ void detect_kernel(const unsigned int* __restrict__ x, int* flag) {
    __shared__ int cnt;
    if (threadIdx.x == 0) cnt = 0;
    __syncthreads();
    int bad = 0;
    for (int i = threadIdx.x; i < 1024; i += 256) {
        unsigned int e = (x[i] >> 7) & 0xFF;
        if (e == 0xFF || (e > 0 && (e < 107 || e > 134))) bad++;
    }
    atomicAdd(&cnt, bad);
    __syncthreads();
    if (threadIdx.x == 0) *flag = (cnt > 256) ? 1 : 0;
}

// Build MFMA B-operand fragments (bf16) and summed f32 biases.
// Bf[b*512 + lane*8 + j] = W_m[k][f], m=b>>1, k=(lane>>4)*8+j,
// f=(b&1)*16+(lane&15)  — the 16x16x32 B-operand layout.
// x side m: [theta_x | theta_deg | theta_r0 | theta_r1]           (8 frags)
// y side m: [gamma_y | gamma_deg | gamma_r0 | gamma_r1 | gamma_x | theta_y]
//                                                                 (12 frags)
__global__ __launch_bounds__(256) void prep_kernel(
    const void* txw, const void* tdw, const void* tyw,
    const void* gyw, const void* gdw, const void* gxw,
    const void* trw, const void* grw,
    const void* txb, const void* tdb, const void* tyb,
    const void* gyb, const void* gdb, const void* gxb,
    const void* trb, const void* grb,
    u16* Bfx, u16* Bfy, float* bx, float* by, const int* flagp)
{
    int f32 = *flagp;
    int t = blockIdx.x * 256 + threadIdx.x;
    if (t < 4096) {
        int b = t >> 9, lane = (t >> 3) & 63, j = t & 7;
        int m = b >> 1;
        int k = ((lane >> 4) << 3) + j;
        int f = ((b & 1) << 4) + (lane & 15);
        size_t idx = (size_t)k * 32 + f;
        float v = (m == 0) ? loadf(txw, idx, f32) : (m == 1) ? loadf(tdw, idx, f32)
                : (m == 2) ? loadf(trw, idx, f32) : loadf(trw, 1024 + idx, f32);
        Bfx[t] = f2bf(v);
    } else if (t < 10240) {
        int e = t - 4096;
        int b = e >> 9, lane = (e >> 3) & 63, j = e & 7;
        int m = b >> 1;
        int k = ((lane >> 4) << 3) + j;
        int f = ((b & 1) << 4) + (lane & 15);
        size_t idx = (size_t)k * 32 + f;
        float v = (m == 0) ? loadf(gyw, idx, f32) : (m == 1) ? loadf(gdw, idx, f32)
                : (m == 2) ? loadf(grw, idx, f32) : (m == 3) ? loadf(grw, 1024 + idx, f32)
                : (m == 4) ? loadf(gxw, idx, f32) : loadf(tyw, idx, f32);
        Bfy[e] = f2bf(v);
    } else if (t < 10304) {
        int f = t - 10240;
        if (f < 32) {
            bx[f] = loadf(txb, f, f32) + loadf(tdb, f, f32) + loadf(tyb, f, f32)
                  + loadf(trb, f, f32) + loadf(trb, 32 + f, f32);
        } else {
            f -= 32;
            by[f] = loadf(gyb, f, f32) + loadf(gdb, f, f32) + loadf(gxb, f, f32)
                  + loadf(grb, f, f32) + loadf(grb, 32 + f, f32);
        }
    }
}

// Pure dtype-normalizing copy: x -> xb (bf16), y -> yb (bf16).
__global__ __launch_bounds__(256) void convert_kernel(
    const void* __restrict__ x, const void* __restrict__ y,
    u16* __restrict__ xb, u16* __restrict__ yb, const int* __restrict__ flagp)
{
    int f32 = *flagp;
    int t = blockIdx.x * 256 + threadIdx.x;
    if (t < NN * 4) {
        int r = t >> 2, q = t & 3;
        uint4 o;
        if (f32) {
            const float4* fp = (const float4*)((const float*)x + (size_t)r * 32 + q * 8);
            float4 v0 = fp[0], v1 = fp[1];
            o.x = pack2(v0.x, v0.y); o.y = pack2(v0.z, v0.w);
            o.z = pack2(v1.x, v1.y); o.w = pack2(v1.z, v1.w);
        } else {
            o = *(const uint4*)((const u16*)x + (size_t)r * 32 + q * 8);
        }
        *(uint4*)(xb + (size_t)r * 32 + q * 8) = o;
    } else if (t < MT * 4) {
        int t2 = t - NN * 4;
        int r = t2 >> 2, q = t2 & 3;
        uint4 o;
        if (f32) {
            const float4* fp = (const float4*)((const float*)y + (size_t)r * 32 + q * 8);
            float4 v0 = fp[0], v1 = fp[1];
            o.x = pack2(v0.x, v0.y); o.y = pack2(v0.z, v0.w);
            o.z = pack2(v1.x, v1.y); o.w = pack2(v1.z, v1.w);
        } else {
            o = *(const uint4*)((const u16*)y + (size_t)r * 32 + q * 8);
        }
        *(uint4*)(yb + (size_t)r * 32 + q * 8) = o;
    }
}

// Per-side body of the merged gather+GEMM kernel.
// IS_Y: stats + ypre (bf16, nt) + xacc scatter (f32 atomics).
// !IS_Y: stores the RAW mfma part to xmfma; apply_bn later adds xacc + relu.
// Index lists staged with stride 17 (16+1 pad): without the pad, the 16
// distinct lr values in a wave map to only 2 LDS banks (stride 64B) -> 8-way
// conflict on every list read (R4: SQ_LDS_BANK_CONFLICT=1.8M).
template<int IS_Y>
__device__ __forceinline__ void fused_body(
    const u16* __restrict__ xb, const u16* __restrict__ yb,
    float* xacc,
    const u16* __restrict__ Bf, const float* __restrict__ bias,
    const void* __restrict__ deg,
    const int* __restrict__ tl, const int* __restrict__ ttl,
    const int* __restrict__ pm_pd, const int* __restrict__ dst,
    float* __restrict__ xmfma, u16* __restrict__ ypre,
    float* __restrict__ ystats, int f32, int sb,
    int* s_t, int* s_tt, float* s_sum, float* s_sq)
{
    const int M = IS_Y ? NE : NN;
    int row0 = sb * 64;
    if (row0 >= M) return;                       // spare block guard
    if (IS_Y && threadIdx.x < 32) { s_sum[threadIdx.x] = 0.f; s_sq[threadIdx.x] = 0.f; }
    int lim = (M - row0) * 16;
    for (int i = threadIdx.x; i < 1024; i += 256) {
        // nt: index lists are stream-once — don't evict gather-table L2 lines
        int v  = (i < lim) ? __builtin_nontemporal_load(&tl[(size_t)row0 * 16 + i])  : 0;
        int v2 = (i < lim) ? __builtin_nontemporal_load(&ttl[(size_t)row0 * 16 + i]) : 0;
        int si = (i >> 4) * 17 + (i & 15);       // padded stride 17
        s_t[si] = v; s_tt[si] = v2;
    }
    __syncthreads();
    int lane = threadIdx.x & 63, wib = threadIdx.x >> 6;
    int r0 = row0 + wib * 16;
    if (r0 + 16 <= M) {   // full waves only (NN,NE are multiples of 16)
        const u16* tab = IS_Y ? yb : xb;
        int m = lane & 15, q = lane >> 4;
        int gr = r0 + m;
        const int* il  = &s_t[(wib * 16 + m) * 17];
        const int* ill = &s_tt[(wib * 16 + m) * 17];

        bf16x8 selfv = *(const bf16x8*)(tab + (size_t)gr * 32 + q * 8);
        union { u16 s[8]; bf16x8 v; } pm;
        if (IS_Y) {
            int ai = pm_pd[gr];
            pm.v = *(const bf16x8*)(xb + (size_t)ai * 32 + q * 8);
        }

        // 32 raw-row gathers, two-buffer staged: 8-16 loads in flight.
        float aT[8]  = {0.f, 0.f, 0.f, 0.f, 0.f, 0.f, 0.f, 0.f};
        float aTT[8] = {0.f, 0.f, 0.f, 0.f, 0.f, 0.f, 0.f, 0.f};
        uint4 ga[8], gb[8];
#pragma unroll
        for (int j = 0; j < 8; ++j)
            ga[j] = *(const uint4*)(tab + (size_t)il[j] * 32 + q * 8);
#pragma unroll
        for (int j = 0; j < 8; ++j)
            gb[j] = *(const uint4*)(tab + (size_t)il[8 + j] * 32 + q * 8);
#pragma unroll
        for (int j = 0; j < 8; ++j) acc8(aT, ga[j]);
#pragma unroll
        for (int j = 0; j < 8; ++j)
            ga[j] = *(const uint4*)(tab + (size_t)ill[j] * 32 + q * 8);
#pragma unroll
        for (int j = 0; j < 8; ++j) acc8(aT, gb[j]);
#pragma unroll
        for (int j = 0; j < 8; ++j)
            gb[j] = *(const uint4*)(tab + (size_t)ill[8 + j] * 32 + q * 8);
#pragma unroll
        for (int j = 0; j < 8; ++j) acc8(aTT, ga[j]);
#pragma unroll
        for (int j = 0; j < 8; ++j) acc8(aTT, gb[j]);

        union { u16 s[8]; bf16x8 v; } ft, ftt;
#pragma unroll
        for (int j = 0; j < 8; ++j) { ft.s[j] = f2bf(aT[j]); ftt.s[j] = f2bf(aTT[j]); }

        const u16* bp = Bf + lane * 8;
#define BFR(b) (*(const bf16x8*)(bp + (b) * 512))
        f32x4 z = {0.f, 0.f, 0.f, 0.f};
        f32x4 a0, a1, d0, d1, c0 = z, c1 = z;
        a0 = __builtin_amdgcn_mfma_f32_16x16x32_bf16(selfv, BFR(0), z, 0, 0, 0);
        a1 = __builtin_amdgcn_mfma_f32_16x16x32_bf16(selfv, BFR(1), z, 0, 0, 0);
        d0 = __builtin_amdgcn_mfma_f32_16x16x32_bf16(selfv, BFR(2), z, 0, 0, 0);
        d1 = __builtin_amdgcn_mfma_f32_16x16x32_bf16(selfv, BFR(3), z, 0, 0, 0);
        a0 = __builtin_amdgcn_mfma_f32_16x16x32_bf16(ft.v,  BFR(4), a0, 0, 0, 0);
        a1 = __builtin_amdgcn_mfma_f32_16x16x32_bf16(ft.v,  BFR(5), a1, 0, 0, 0);
        a0 = __builtin_amdgcn_mfma_f32_16x16x32_bf16(ftt.v, BFR(6), a0, 0, 0, 0);
        a1 = __builtin_amdgcn_mfma_f32_16x16x32_bf16(ftt.v, BFR(7), a1, 0, 0, 0);
        if (IS_Y) {
            a0 = __builtin_amdgcn_mfma_f32_16x16x32_bf16(pm.v,  BFR(8),  a0, 0, 0, 0);
            a1 = __builtin_amdgcn_mfma_f32_16x16x32_bf16(pm.v,  BFR(9),  a1, 0, 0, 0);
            c0 = __builtin_amdgcn_mfma_f32_16x16x32_bf16(selfv, BFR(10), z, 0, 0, 0);
            c1 = __builtin_amdgcn_mfma_f32_16x16x32_bf16(selfv, BFR(11), z, 0, 0, 0);
        }
#undef BFR

        // D layout: col = lane&15 (=m), row = q*4 + i
        int n = m;
        int rowb = r0 + q * 4;
        float bl_ = bias[n], bh_ = bias[16 + n];
        float s0 = 0.f, q0 = 0.f, s1 = 0.f, q1 = 0.f;
#pragma unroll
        for (int i = 0; i < 4; ++i) {
            float dgi = loadf(deg, rowb + i, f32);
            size_t ro = (size_t)(rowb + i) * 32;
            float lo = a0[i] + dgi * d0[i] + bl_;
            float hi = a1[i] + dgi * d1[i] + bh_;
            if (!IS_Y) {
                // raw mfma part; xacc add + relu + stats happen downstream
                __builtin_nontemporal_store(lo, &xmfma[ro + n]);
                __builtin_nontemporal_store(hi, &xmfma[ro + 16 + n]);
            } else {
                hi = fmaxf(hi, 0.f);
                __builtin_nontemporal_store(f2bf(lo), &ypre[ro + n]);
                __builtin_nontemporal_store(f2bf(hi), &ypre[ro + 16 + n]);
                int d = dst[rowb + i];
                float* p = xacc + (size_t)d * 32;
                atomicAdd(p + n,      c0[i]);
                atomicAdd(p + 16 + n, c1[i]);
                s0 += lo; q0 += lo * lo;
                s1 += hi; q1 += hi * hi;
            }
        }
        if (IS_Y) {
            // cross-lane pre-reduce over the 4 lanes sharing n (lane, lane^16,
            // lane^32) before the shared atomic: 1024 -> 256 LDS atomics/block
            s0 += __shfl_xor(s0, 16); s0 += __shfl_xor(s0, 32);
            q0 += __shfl_xor(q0, 16); q0 += __shfl_xor(q0, 32);
            s1 += __shfl_xor(s1, 16); s1 += __shfl_xor(s1, 32);
            q1 += __shfl_xor(q1, 16); q1 += __shfl_xor(q1, 32);
            if (lane < 16) {
                atomicAdd(&s_sum[n], s0);      atomicAdd(&s_sq[n], q0);
                atomicAdd(&s_sum[16 + n], s1); atomicAdd(&s_sq[16 + n], q1);
            }
        }
    }
    if (IS_Y) {
        __syncthreads();
        if (threadIdx.x < 32) {
            atomicAdd(&ystats[threadIdx.x], s_sum[threadIdx.x]);
            atomicAdd(&ystats[32 + threadIdx.x], s_sq[threadIdx.x]);
        }
    }
}

// Merged launch: mod-3 block interleave (2 y-blocks : 1 x-block) keeps both
// sides' traffic mixed on the TCC-miss path for the whole kernel.
__global__ __launch_bounds__(256, 4) void fused_both(
    const u16* __restrict__ xb, const u16* __restrict__ yb, float* xacc,
    const u16* __restrict__ Bfx, const u16* __restrict__ Bfy,
    const float* __restrict__ bx, const float* __restrict__ by,
    const void* __restrict__ deg_g, const void* __restrict__ deg_lg,
    const int* __restrict__ t_g, const int* __restrict__ tt_g,
    const int* __restrict__ t_lg, const int* __restrict__ tt_lg,
    const int* __restrict__ pm_pd, const int* __restrict__ dst,
    float* __restrict__ xmfma, u16* __restrict__ ypre,
    float* __restrict__ stats, const int* __restrict__ flagp)
{
    __shared__ int s_t[1088];        // 64 rows x (16+1 pad)
    __shared__ int s_tt[1088];
    __shared__ float s_sum[32];
    __shared__ float s_sq[32];
    int f32 = *flagp;
    int bid = blockIdx.x;
    int s = bid % 3;
    if (s == 2) {
        fused_body<0>(xb, yb, xacc, Bfx, bx, deg_g, t_g, tt_g, pm_pd, dst,
                      xmfma, ypre, stats, f32, bid / 3,
                      s_t, s_tt, s_sum, s_sq);
    } else {
        fused_body<1>(xb, yb, xacc, Bfy, by, deg_lg, t_lg, tt_lg, pm_pd, dst,
                      xmfma, ypre, stats + 64, f32, (bid / 3) * 2 + s,
                      s_t, s_tt, s_sum, s_sq);
    }
}

// x stats only (no store): reads xmfma + xacc, computes final pre-BN values
// in-register, accumulates BN stats. apply_bn recomputes the same sum.
__global__ __launch_bounds__(256) void xstats_kernel(
    const float* __restrict__ xmfma, const float* __restrict__ xacc,
    float* __restrict__ stats)
{
    __shared__ float s_sum[32];
    __shared__ float s_sq[32];
    if (threadIdx.x < 32) { s_sum[threadIdx.x] = 0.f; s_sq[threadIdx.x] = 0.f; }
    __syncthreads();
    int tid = blockIdx.x * 256 + threadIdx.x;    // NN*8 threads, 4 elems each
    int fq = (tid & 7) * 4;
    float4 a = ((const float4*)xmfma)[tid];
    float4 b = ((const float4*)xacc)[tid];
    float sv[4], qv[4];
    sv[0] = a.x + b.x; sv[1] = a.y + b.y; sv[2] = a.z + b.z; sv[3] = a.w + b.w;
    if (fq >= 16) {
#pragma unroll
        for (int i = 0; i < 4; ++i) sv[i] = fmaxf(sv[i], 0.f);
    }
#pragma unroll
    for (int i = 0; i < 4; ++i) qv[i] = sv[i] * sv[i];
    // cross-lane pre-reduce over the 8 lanes sharing fq (xor 8,16,32)
#pragma unroll
    for (int off = 8; off < 64; off <<= 1) {
#pragma unroll
        for (int i = 0; i < 4; ++i) {
            sv[i] += __shfl_xor(sv[i], off);
            qv[i] += __shfl_xor(qv[i], off);
        }
    }
    int lane = threadIdx.x & 63;
    if (lane < 8) {
        int f0 = lane * 4;
#pragma unroll
        for (int i = 0; i < 4; ++i) {
            atomicAdd(&s_sum[f0 + i], sv[i]);
            atomicAdd(&s_sq[f0 + i], qv[i]);
        }
    }
    __syncthreads();
    if (threadIdx.x < 32) {
        atomicAdd(&stats[threadIdx.x], s_sum[threadIdx.x]);
        atomicAdd(&stats[32 + threadIdx.x], s_sq[threadIdx.x]);
    }
}

__global__ void finalize_stats(
    const float* stats,
    const void* bnxw, const void* bnxb, const void* bnyw, const void* bnyb,
    float* scsh, const int* flagp)
{
    int f32 = *flagp;
    int f = threadIdx.x;
    if (f < 32) {
        float m = stats[f] / (float)NN;
        float var = stats[32 + f] / (float)NN - m * m;
        float inv = rsqrtf(var + 1e-5f);
        float sc = loadf(bnxw, f, f32) * inv;
        scsh[f] = sc; scsh[32 + f] = loadf(bnxb, f, f32) - m * sc;
    } else if (f < 64) {
        int g = f - 32;
        float m = stats[64 + g] / (float)NE;
        float var = stats[96 + g] / (float)NE - m * m;
        float inv = rsqrtf(var + 1e-5f);
        float sc = loadf(bnyw, g, f32) * inv;
        scsh[64 + g] = sc; scsh[96 + g] = loadf(bnyb, g, f32) - m * sc;
    }
}

__global__ __launch_bounds__(256) void apply_bn(
    const float* __restrict__ xmfma, const float* __restrict__ xacc,
    const u16* __restrict__ ypre,
    const float* __restrict__ scsh, void* __restrict__ out,
    const int* __restrict__ flagp)
{
    int f32 = *flagp;
    int tid = blockIdx.x * 256 + threadIdx.x;   // MT*8 threads, 4 elems each
    if (tid >= MT * 8) return;
    int fq = (tid & 7) * 4;
    const float* sc;
    float4 v;
    if (tid < NN * 8) {
        float4 a = ((const float4*)xmfma)[tid];
        float4 b = ((const float4*)xacc)[tid];
        v.x = a.x + b.x; v.y = a.y + b.y; v.z = a.z + b.z; v.w = a.w + b.w;
        if (fq >= 16) {
            v.x = fmaxf(v.x, 0.f); v.y = fmaxf(v.y, 0.f);
            v.z = fmaxf(v.z, 0.f); v.w = fmaxf(v.w, 0.f);
        }
        sc = scsh;
    } else {
        size_t off = (size_t)tid * 4 - (size_t)NN * 32;
        ushort4 u = *(const ushort4*)(ypre + off);
        v.x = bf2f(u.x); v.y = bf2f(u.y); v.z = bf2f(u.z); v.w = bf2f(u.w);
        sc = scsh + 64;
    }
    float o0 = v.x * sc[fq + 0] + sc[32 + fq + 0];
    float o1 = v.y * sc[fq + 1] + sc[32 + fq + 1];
    float o2 = v.z * sc[fq + 2] + sc[32 + fq + 2];
    float o3 = v.w * sc[fq + 3] + sc[32 + fq + 3];
    if (f32) {
        float4 o; o.x = o0; o.y = o1; o.z = o2; o.w = o3;
        ((float4*)out)[tid] = o;
    } else {
        ushort4 o; o.x = f2bf(o0); o.y = f2bf(o1); o.z = f2bf(o2); o.w = f2bf(o3);
        ((ushort4*)out)[tid] = o;
    }
}

extern "C" void kernel_launch(void* const* d_in, const int* in_sizes, int n_in,
                              void* d_out, int out_size, void* d_ws, size_t ws_size,
                              hipStream_t stream)
{
    const void* x      = d_in[0];
    const void* y      = d_in[1];
    const void* deg_g  = d_in[2];
    const void* deg_lg = d_in[3];
    const int* t_g   = (const int*)d_in[4];
    const int* tt_g  = (const int*)d_in[5];
    const int* t_lg  = (const int*)d_in[6];
    const int* tt_lg = (const int*)d_in[7];
    const int* dst   = (const int*)d_in[8];
    const int* pm_pd = (const int*)d_in[9];

    char* ws = (char*)d_ws;
    int*   flag = (int*)ws;                     // 4 B
    u16* Bfx   = (u16*)(ws + 256);              // 4096 u16 = 8 KB
    u16* Bfy   = Bfx + 4096;                    // 6144 u16 = 12 KB
    float* bx  = (float*)(ws + 24576);          // 32 f32
    float* by  = bx + 32;
    float* stats = by + 32;                     // 128 f32
    float* scsh  = stats + 128;                 // 128 f32
    u16* xb    = (u16*)(ws + 65536);            // NN*32 bf16 = 6.4 MB
    u16* yb    = xb + (size_t)NN * 32;          // NE*32 bf16 = 12.8 MB
    float* xacc = (float*)(yb + (size_t)NE * 32); // NN*32 f32 = 12.8 MB
    u16* ypre  = (u16*)(xacc + (size_t)NN * 32);  // NE*32 bf16 = 12.8 MB
    float* xmfma = (float*)(ypre + (size_t)NE * 32); // NN*32 f32 = 12.8 MB
    // total ≈ 64 KB + 57.6 MB

    hipMemsetAsync(stats, 0, 256 * sizeof(float), stream);
    hipMemsetAsync(xacc, 0, (size_t)NN * 32 * sizeof(float), stream);

    detect_kernel<<<1, 256, 0, stream>>>((const unsigned int*)x, flag);
    prep_kernel<<<41, 256, 0, stream>>>(
        d_in[10], d_in[12], d_in[14], d_in[16], d_in[18], d_in[20],
        d_in[22], d_in[24],
        d_in[11], d_in[13], d_in[15], d_in[17], d_in[19], d_in[21],
        d_in[23], d_in[25],
        Bfx, Bfy, bx, by, flag);
    convert_kernel<<<4688, 256, 0, stream>>>(x, y, xb, yb, flag);
    // one launch, both sides interleaved: 3125 y-blocks + 1563 x-blocks
    // (+1 guarded spare) via mod-3 mapping.
    fused_both<<<4689, 256, 0, stream>>>(xb, yb, xacc, Bfx, Bfy, bx, by,
                                         deg_g, deg_lg, t_g, tt_g, t_lg, tt_lg,
                                         pm_pd, dst, xmfma, ypre, stats, flag);
    xstats_kernel<<<3125, 256, 0, stream>>>(xmfma, xacc, stats);
    finalize_stats<<<1, 64, 0, stream>>>(stats, d_in[26], d_in[27], d_in[28],
                                         d_in[29], scsh, flag);
    apply_bn<<<9375, 256, 0, stream>>>(xmfma, xacc, ypre, scsh, d_out, flag);
}

// Round 6
// 437.210 us; speedup vs baseline: 1.2413x; 1.2413x over previous
//
#include <hip/hip_runtime.h>

#define NN 100000
#define NE 200000
#define MT (NN + NE)

typedef unsigned short u16;
typedef __attribute__((ext_vector_type(8))) short bf16x8;
typedef __attribute__((ext_vector_type(4))) float f32x4;

__device__ __forceinline__ float bf2f(u16 u) {
    union { unsigned int i; float f; } v; v.i = ((unsigned int)u) << 16; return v.f;
}
__device__ __forceinline__ u16 f2bf(float f) {
    union { unsigned int i; float f; } v; v.f = f;
    unsigned int r = v.i + 0x7fffu + ((v.i >> 16) & 1u);
    return (u16)(r >> 16);
}
__device__ __forceinline__ void unpack2(unsigned int u, float& lo, float& hi) {
    union { unsigned int i; float f; } a, b;
    a.i = u << 16; b.i = u & 0xffff0000u;
    lo = a.f; hi = b.f;
}
__device__ __forceinline__ unsigned int pack2(float a, float b) {
    return (unsigned int)f2bf(a) | ((unsigned int)f2bf(b) << 16);
}
// Dtype-flexible scalar load (R2-R4 proven): f32 flag ? float : bf16.
__device__ __forceinline__ float loadf(const void* p, size_t i, int f32) {
    return f32 ? ((const float*)p)[i] : bf2f(((const u16*)p)[i]);
}
__device__ __forceinline__ void acc8(float a[8], uint4 g) {
    float e0, e1, e2, e3, e4, e5, e6, e7;
    unpack2(g.x, e0, e1); unpack2(g.y, e2, e3);
    unpack2(g.z, e4, e5); unpack2(g.w, e6, e7);
    a[0] += e0; a[1] += e1; a[2] += e2; a[3] += e3;
    a[4] += e4; a[5] += e5; a[6] += e6; a[7] += e7;
}

// Detect input dtype from bit patterns of x (R2-R4 proven). flag=1 => fp32.
__global__ void detect_kernel(const unsigned int* __restrict__ x, int* flag) {
    __shared__ int cnt;
    if (threadIdx.x == 0) cnt = 0;
    __syncthreads();
    int bad = 0;
    for (int i = threadIdx.x; i < 1024; i += 256) {
        unsigned int e = (x[i] >> 7) & 0xFF;
        if (e == 0xFF || (e > 0 && (e < 107 || e > 134))) bad++;
    }
    atomicAdd(&cnt, bad);
    __syncthreads();
    if (threadIdx.x == 0) *flag = (cnt > 256) ? 1 : 0;
}

// Build MFMA B-operand fragments (bf16) and summed f32 biases.
// Bf[b*512 + lane*8 + j] = W_m[k][f], m=b>>1, k=(lane>>4)*8+j,
// f=(b&1)*16+(lane&15)  — the 16x16x32 B-operand layout.
// x side m: [theta_x | theta_deg | theta_r0 | theta_r1]           (8 frags)
// y side m: [gamma_y | gamma_deg | gamma_r0 | gamma_r1 | gamma_x | theta_y]
//                                                                 (12 frags)
__global__ __launch_bounds__(256) void prep_kernel(
    const void* txw, const void* tdw, const void* tyw,
    const void* gyw, const void* gdw, const void* gxw,
    const void* trw, const void* grw,
    const void* txb, const void* tdb, const void* tyb,
    const void* gyb, const void* gdb, const void* gxb,
    const void* trb, const void* grb,
    u16* Bfx, u16* Bfy, float* bx, float* by, const int* flagp)
{
    int f32 = *flagp;
    int t = blockIdx.x * 256 + threadIdx.x;
    if (t < 4096) {
        int b = t >> 9, lane = (t >> 3) & 63, j = t & 7;
        int m = b >> 1;
        int k = ((lane >> 4) << 3) + j;
        int f = ((b & 1) << 4) + (lane & 15);
        size_t idx = (size_t)k * 32 + f;
        float v = (m == 0) ? loadf(txw, idx, f32) : (m == 1) ? loadf(tdw, idx, f32)
                : (m == 2) ? loadf(trw, idx, f32) : loadf(trw, 1024 + idx, f32);
        Bfx[t] = f2bf(v);
    } else if (t < 10240) {
        int e = t - 4096;
        int b = e >> 9, lane = (e >> 3) & 63, j = e & 7;
        int m = b >> 1;
        int k = ((lane >> 4) << 3) + j;
        int f = ((b & 1) << 4) + (lane & 15);
        size_t idx = (size_t)k * 32 + f;
        float v = (m == 0) ? loadf(gyw, idx, f32) : (m == 1) ? loadf(gdw, idx, f32)
                : (m == 2) ? loadf(grw, idx, f32) : (m == 3) ? loadf(grw, 1024 + idx, f32)
                : (m == 4) ? loadf(gxw, idx, f32) : loadf(tyw, idx, f32);
        Bfy[e] = f2bf(v);
    } else if (t < 10304) {
        int f = t - 10240;
        if (f < 32) {
            bx[f] = loadf(txb, f, f32) + loadf(tdb, f, f32) + loadf(tyb, f, f32)
                  + loadf(trb, f, f32) + loadf(trb, 32 + f, f32);
        } else {
            f -= 32;
            by[f] = loadf(gyb, f, f32) + loadf(gdb, f, f32) + loadf(gxb, f, f32)
                  + loadf(grb, f, f32) + loadf(grb, 32 + f, f32);
        }
    }
}

// Pure dtype-normalizing copy: x -> xb (bf16), y -> yb (bf16).
__global__ __launch_bounds__(256) void convert_kernel(
    const void* __restrict__ x, const void* __restrict__ y,
    u16* __restrict__ xb, u16* __restrict__ yb, const int* __restrict__ flagp)
{
    int f32 = *flagp;
    int t = blockIdx.x * 256 + threadIdx.x;
    if (t < NN * 4) {
        int r = t >> 2, q = t & 3;
        uint4 o;
        if (f32) {
            const float4* fp = (const float4*)((const float*)x + (size_t)r * 32 + q * 8);
            float4 v0 = fp[0], v1 = fp[1];
            o.x = pack2(v0.x, v0.y); o.y = pack2(v0.z, v0.w);
            o.z = pack2(v1.x, v1.y); o.w = pack2(v1.z, v1.w);
        } else {
            o = *(const uint4*)((const u16*)x + (size_t)r * 32 + q * 8);
        }
        *(uint4*)(xb + (size_t)r * 32 + q * 8) = o;
    } else if (t < MT * 4) {
        int t2 = t - NN * 4;
        int r = t2 >> 2, q = t2 & 3;
        uint4 o;
        if (f32) {
            const float4* fp = (const float4*)((const float*)y + (size_t)r * 32 + q * 8);
            float4 v0 = fp[0], v1 = fp[1];
            o.x = pack2(v0.x, v0.y); o.y = pack2(v0.z, v0.w);
            o.z = pack2(v1.x, v1.y); o.w = pack2(v1.z, v1.w);
        } else {
            o = *(const uint4*)((const u16*)y + (size_t)r * 32 + q * 8);
        }
        *(uint4*)(yb + (size_t)r * 32 + q * 8) = o;
    }
}

// Per-side body of the merged gather+GEMM kernel.
// IS_Y: stats + ypre (bf16, nt) + xacc scatter (f32 atomics).
// !IS_Y: stores the RAW mfma part to xmfma; apply_bn later adds xacc + relu.
// Index lists staged with stride 17 (16+1 pad): R4->R5 proved this cuts
// SQ_LDS_BANK_CONFLICT 1.8M -> 300K.
template<int IS_Y>
__device__ __forceinline__ void fused_body(
    const u16* __restrict__ xb, const u16* __restrict__ yb,
    float* xacc,
    const u16* __restrict__ Bf, const float* __restrict__ bias,
    const void* __restrict__ deg,
    const int* __restrict__ tl, const int* __restrict__ ttl,
    const int* __restrict__ pm_pd, const int* __restrict__ dst,
    float* __restrict__ xmfma, u16* __restrict__ ypre,
    float* __restrict__ ystats, int f32, int sb,
    int* s_t, int* s_tt, float* s_sum, float* s_sq)
{
    const int M = IS_Y ? NE : NN;
    int row0 = sb * 64;
    if (row0 >= M) return;                       // spare block guard
    if (IS_Y && threadIdx.x < 32) { s_sum[threadIdx.x] = 0.f; s_sq[threadIdx.x] = 0.f; }
    int lim = (M - row0) * 16;
    for (int i = threadIdx.x; i < 1024; i += 256) {
        // nt: index lists are stream-once — don't evict gather-table L2 lines
        int v  = (i < lim) ? __builtin_nontemporal_load(&tl[(size_t)row0 * 16 + i])  : 0;
        int v2 = (i < lim) ? __builtin_nontemporal_load(&ttl[(size_t)row0 * 16 + i]) : 0;
        int si = (i >> 4) * 17 + (i & 15);       // padded stride 17
        s_t[si] = v; s_tt[si] = v2;
    }
    __syncthreads();
    int lane = threadIdx.x & 63, wib = threadIdx.x >> 6;
    int r0 = row0 + wib * 16;
    if (r0 + 16 <= M) {   // full waves only (NN,NE are multiples of 16)
        const u16* tab = IS_Y ? yb : xb;
        int m = lane & 15, q = lane >> 4;
        int gr = r0 + m;
        const int* il  = &s_t[(wib * 16 + m) * 17];
        const int* ill = &s_tt[(wib * 16 + m) * 17];

        bf16x8 selfv = *(const bf16x8*)(tab + (size_t)gr * 32 + q * 8);
        union { u16 s[8]; bf16x8 v; } pm;
        if (IS_Y) {
            int ai = pm_pd[gr];
            pm.v = *(const bf16x8*)(xb + (size_t)ai * 32 + q * 8);
        }

        // 32 raw-row gathers, two-buffer staged: 8-16 loads in flight.
        float aT[8]  = {0.f, 0.f, 0.f, 0.f, 0.f, 0.f, 0.f, 0.f};
        float aTT[8] = {0.f, 0.f, 0.f, 0.f, 0.f, 0.f, 0.f, 0.f};
        uint4 ga[8], gb[8];
#pragma unroll
        for (int j = 0; j < 8; ++j)
            ga[j] = *(const uint4*)(tab + (size_t)il[j] * 32 + q * 8);
#pragma unroll
        for (int j = 0; j < 8; ++j)
            gb[j] = *(const uint4*)(tab + (size_t)il[8 + j] * 32 + q * 8);
#pragma unroll
        for (int j = 0; j < 8; ++j) acc8(aT, ga[j]);
#pragma unroll
        for (int j = 0; j < 8; ++j)
            ga[j] = *(const uint4*)(tab + (size_t)ill[j] * 32 + q * 8);
#pragma unroll
        for (int j = 0; j < 8; ++j) acc8(aT, gb[j]);
#pragma unroll
        for (int j = 0; j < 8; ++j)
            gb[j] = *(const uint4*)(tab + (size_t)ill[8 + j] * 32 + q * 8);
#pragma unroll
        for (int j = 0; j < 8; ++j) acc8(aTT, ga[j]);
#pragma unroll
        for (int j = 0; j < 8; ++j) acc8(aTT, gb[j]);

        union { u16 s[8]; bf16x8 v; } ft, ftt;
#pragma unroll
        for (int j = 0; j < 8; ++j) { ft.s[j] = f2bf(aT[j]); ftt.s[j] = f2bf(aTT[j]); }

        const u16* bp = Bf + lane * 8;
#define BFR(b) (*(const bf16x8*)(bp + (b) * 512))
        f32x4 z = {0.f, 0.f, 0.f, 0.f};
        f32x4 a0, a1, d0, d1, c0 = z, c1 = z;
        a0 = __builtin_amdgcn_mfma_f32_16x16x32_bf16(selfv, BFR(0), z, 0, 0, 0);
        a1 = __builtin_amdgcn_mfma_f32_16x16x32_bf16(selfv, BFR(1), z, 0, 0, 0);
        d0 = __builtin_amdgcn_mfma_f32_16x16x32_bf16(selfv, BFR(2), z, 0, 0, 0);
        d1 = __builtin_amdgcn_mfma_f32_16x16x32_bf16(selfv, BFR(3), z, 0, 0, 0);
        a0 = __builtin_amdgcn_mfma_f32_16x16x32_bf16(ft.v,  BFR(4), a0, 0, 0, 0);
        a1 = __builtin_amdgcn_mfma_f32_16x16x32_bf16(ft.v,  BFR(5), a1, 0, 0, 0);
        a0 = __builtin_amdgcn_mfma_f32_16x16x32_bf16(ftt.v, BFR(6), a0, 0, 0, 0);
        a1 = __builtin_amdgcn_mfma_f32_16x16x32_bf16(ftt.v, BFR(7), a1, 0, 0, 0);
        if (IS_Y) {
            a0 = __builtin_amdgcn_mfma_f32_16x16x32_bf16(pm.v,  BFR(8),  a0, 0, 0, 0);
            a1 = __builtin_amdgcn_mfma_f32_16x16x32_bf16(pm.v,  BFR(9),  a1, 0, 0, 0);
            c0 = __builtin_amdgcn_mfma_f32_16x16x32_bf16(selfv, BFR(10), z, 0, 0, 0);
            c1 = __builtin_amdgcn_mfma_f32_16x16x32_bf16(selfv, BFR(11), z, 0, 0, 0);
        }
#undef BFR

        // D layout: col = lane&15 (=m), row = q*4 + i
        int n = m;
        int rowb = r0 + q * 4;
        float bl_ = bias[n], bh_ = bias[16 + n];
        float s0 = 0.f, q0 = 0.f, s1 = 0.f, q1 = 0.f;
#pragma unroll
        for (int i = 0; i < 4; ++i) {
            float dgi = loadf(deg, rowb + i, f32);
            size_t ro = (size_t)(rowb + i) * 32;
            float lo = a0[i] + dgi * d0[i] + bl_;
            float hi = a1[i] + dgi * d1[i] + bh_;
            if (!IS_Y) {
                // raw mfma part; xacc add + relu + stats happen downstream
                __builtin_nontemporal_store(lo, &xmfma[ro + n]);
                __builtin_nontemporal_store(hi, &xmfma[ro + 16 + n]);
            } else {
                hi = fmaxf(hi, 0.f);
                __builtin_nontemporal_store(f2bf(lo), &ypre[ro + n]);
                __builtin_nontemporal_store(f2bf(hi), &ypre[ro + 16 + n]);
                int d = dst[rowb + i];
                float* p = xacc + (size_t)d * 32;
                atomicAdd(p + n,      c0[i]);
                atomicAdd(p + 16 + n, c1[i]);
                s0 += lo; q0 += lo * lo;
                s1 += hi; q1 += hi * hi;
            }
        }
        if (IS_Y) {
            // cross-lane pre-reduce over the 4 lanes sharing n (lane, lane^16,
            // lane^32) before the shared atomic: 1024 -> 256 LDS atomics/block
            s0 += __shfl_xor(s0, 16); s0 += __shfl_xor(s0, 32);
            q0 += __shfl_xor(q0, 16); q0 += __shfl_xor(q0, 32);
            s1 += __shfl_xor(s1, 16); s1 += __shfl_xor(s1, 32);
            q1 += __shfl_xor(q1, 16); q1 += __shfl_xor(q1, 32);
            if (lane < 16) {
                atomicAdd(&s_sum[n], s0);      atomicAdd(&s_sq[n], q0);
                atomicAdd(&s_sum[16 + n], s1); atomicAdd(&s_sq[16 + n], q1);
            }
        }
    }
    if (IS_Y) {
        __syncthreads();
        if (threadIdx.x < 32) {
            atomicAdd(&ystats[threadIdx.x], s_sum[threadIdx.x]);
            atomicAdd(&ystats[32 + threadIdx.x], s_sq[threadIdx.x]);
        }
    }
}

// Merged launch: mod-3 block interleave (2 y-blocks : 1 x-block) keeps both
// sides' traffic mixed on the TCC-miss path for the whole kernel.
// (256,3): R5 proved (256,4) forces VGPR 84->64 and spills the 16 staging
// uint4s to scratch (+289MB write, +180MB fetch, 181->280us). Keep 3.
__global__ __launch_bounds__(256, 3) void fused_both(
    const u16* __restrict__ xb, const u16* __restrict__ yb, float* xacc,
    const u16* __restrict__ Bfx, const u16* __restrict__ Bfy,
    const float* __restrict__ bx, const float* __restrict__ by,
    const void* __restrict__ deg_g, const void* __restrict__ deg_lg,
    const int* __restrict__ t_g, const int* __restrict__ tt_g,
    const int* __restrict__ t_lg, const int* __restrict__ tt_lg,
    const int* __restrict__ pm_pd, const int* __restrict__ dst,
    float* __restrict__ xmfma, u16* __restrict__ ypre,
    float* __restrict__ stats, const int* __restrict__ flagp)
{
    __shared__ int s_t[1088];        // 64 rows x (16+1 pad)
    __shared__ int s_tt[1088];
    __shared__ float s_sum[32];
    __shared__ float s_sq[32];
    int f32 = *flagp;
    int bid = blockIdx.x;
    int s = bid % 3;
    if (s == 2) {
        fused_body<0>(xb, yb, xacc, Bfx, bx, deg_g, t_g, tt_g, pm_pd, dst,
                      xmfma, ypre, stats, f32, bid / 3,
                      s_t, s_tt, s_sum, s_sq);
    } else {
        fused_body<1>(xb, yb, xacc, Bfy, by, deg_lg, t_lg, tt_lg, pm_pd, dst,
                      xmfma, ypre, stats + 64, f32, (bid / 3) * 2 + s,
                      s_t, s_tt, s_sum, s_sq);
    }
}

// x stats only (no store): reads xmfma + xacc, computes final pre-BN values
// in-register, accumulates BN stats. apply_bn recomputes the same sum.
__global__ __launch_bounds__(256) void xstats_kernel(
    const float* __restrict__ xmfma, const float* __restrict__ xacc,
    float* __restrict__ stats)
{
    __shared__ float s_sum[32];
    __shared__ float s_sq[32];
    if (threadIdx.x < 32) { s_sum[threadIdx.x] = 0.f; s_sq[threadIdx.x] = 0.f; }
    __syncthreads();
    int tid = blockIdx.x * 256 + threadIdx.x;    // NN*8 threads, 4 elems each
    int fq = (tid & 7) * 4;
    float4 a = ((const float4*)xmfma)[tid];
    float4 b = ((const float4*)xacc)[tid];
    float sv[4], qv[4];
    sv[0] = a.x + b.x; sv[1] = a.y + b.y; sv[2] = a.z + b.z; sv[3] = a.w + b.w;
    if (fq >= 16) {
#pragma unroll
        for (int i = 0; i < 4; ++i) sv[i] = fmaxf(sv[i], 0.f);
    }
#pragma unroll
    for (int i = 0; i < 4; ++i) qv[i] = sv[i] * sv[i];
    // cross-lane pre-reduce over the 8 lanes sharing fq (xor 8,16,32)
#pragma unroll
    for (int off = 8; off < 64; off <<= 1) {
#pragma unroll
        for (int i = 0; i < 4; ++i) {
            sv[i] += __shfl_xor(sv[i], off);
            qv[i] += __shfl_xor(qv[i], off);
        }
    }
    int lane = threadIdx.x & 63;
    if (lane < 8) {
        int f0 = lane * 4;
#pragma unroll
        for (int i = 0; i < 4; ++i) {
            atomicAdd(&s_sum[f0 + i], sv[i]);
            atomicAdd(&s_sq[f0 + i], qv[i]);
        }
    }
    __syncthreads();
    if (threadIdx.x < 32) {
        atomicAdd(&stats[threadIdx.x], s_sum[threadIdx.x]);
        atomicAdd(&stats[32 + threadIdx.x], s_sq[threadIdx.x]);
    }
}

__global__ void finalize_stats(
    const float* stats,
    const void* bnxw, const void* bnxb, const void* bnyw, const void* bnyb,
    float* scsh, const int* flagp)
{
    int f32 = *flagp;
    int f = threadIdx.x;
    if (f < 32) {
        float m = stats[f] / (float)NN;
        float var = stats[32 + f] / (float)NN - m * m;
        float inv = rsqrtf(var + 1e-5f);
        float sc = loadf(bnxw, f, f32) * inv;
        scsh[f] = sc; scsh[32 + f] = loadf(bnxb, f, f32) - m * sc;
    } else if (f < 64) {
        int g = f - 32;
        float m = stats[64 + g] / (float)NE;
        float var = stats[96 + g] / (float)NE - m * m;
        float inv = rsqrtf(var + 1e-5f);
        float sc = loadf(bnyw, g, f32) * inv;
        scsh[64 + g] = sc; scsh[96 + g] = loadf(bnyb, g, f32) - m * sc;
    }
}

__global__ __launch_bounds__(256) void apply_bn(
    const float* __restrict__ xmfma, const float* __restrict__ xacc,
    const u16* __restrict__ ypre,
    const float* __restrict__ scsh, void* __restrict__ out,
    const int* __restrict__ flagp)
{
    int f32 = *flagp;
    int tid = blockIdx.x * 256 + threadIdx.x;   // MT*8 threads, 4 elems each
    if (tid >= MT * 8) return;
    int fq = (tid & 7) * 4;
    const float* sc;
    float4 v;
    if (tid < NN * 8) {
        float4 a = ((const float4*)xmfma)[tid];
        float4 b = ((const float4*)xacc)[tid];
        v.x = a.x + b.x; v.y = a.y + b.y; v.z = a.z + b.z; v.w = a.w + b.w;
        if (fq >= 16) {
            v.x = fmaxf(v.x, 0.f); v.y = fmaxf(v.y, 0.f);
            v.z = fmaxf(v.z, 0.f); v.w = fmaxf(v.w, 0.f);
        }
        sc = scsh;
    } else {
        size_t off = (size_t)tid * 4 - (size_t)NN * 32;
        ushort4 u = *(const ushort4*)(ypre + off);
        v.x = bf2f(u.x); v.y = bf2f(u.y); v.z = bf2f(u.z); v.w = bf2f(u.w);
        sc = scsh + 64;
    }
    float o0 = v.x * sc[fq + 0] + sc[32 + fq + 0];
    float o1 = v.y * sc[fq + 1] + sc[32 + fq + 1];
    float o2 = v.z * sc[fq + 2] + sc[32 + fq + 2];
    float o3 = v.w * sc[fq + 3] + sc[32 + fq + 3];
    if (f32) {
        float4 o; o.x = o0; o.y = o1; o.z = o2; o.w = o3;
        ((float4*)out)[tid] = o;
    } else {
        ushort4 o; o.x = f2bf(o0); o.y = f2bf(o1); o.z = f2bf(o2); o.w = f2bf(o3);
        ((ushort4*)out)[tid] = o;
    }
}

extern "C" void kernel_launch(void* const* d_in, const int* in_sizes, int n_in,
                              void* d_out, int out_size, void* d_ws, size_t ws_size,
                              hipStream_t stream)
{
    const void* x      = d_in[0];
    const void* y      = d_in[1];
    const void* deg_g  = d_in[2];
    const void* deg_lg = d_in[3];
    const int* t_g   = (const int*)d_in[4];
    const int* tt_g  = (const int*)d_in[5];
    const int* t_lg  = (const int*)d_in[6];
    const int* tt_lg = (const int*)d_in[7];
    const int* dst   = (const int*)d_in[8];
    const int* pm_pd = (const int*)d_in[9];

    char* ws = (char*)d_ws;
    int*   flag = (int*)ws;                     // 4 B
    u16* Bfx   = (u16*)(ws + 256);              // 4096 u16 = 8 KB
    u16* Bfy   = Bfx + 4096;                    // 6144 u16 = 12 KB
    float* bx  = (float*)(ws + 24576);          // 32 f32
    float* by  = bx + 32;
    float* stats = by + 32;                     // 128 f32
    float* scsh  = stats + 128;                 // 128 f32
    u16* xb    = (u16*)(ws + 65536);            // NN*32 bf16 = 6.4 MB
    u16* yb    = xb + (size_t)NN * 32;          // NE*32 bf16 = 12.8 MB
    float* xacc = (float*)(yb + (size_t)NE * 32); // NN*32 f32 = 12.8 MB
    u16* ypre  = (u16*)(xacc + (size_t)NN * 32);  // NE*32 bf16 = 12.8 MB
    float* xmfma = (float*)(ypre + (size_t)NE * 32); // NN*32 f32 = 12.8 MB
    // total ≈ 64 KB + 57.6 MB

    hipMemsetAsync(stats, 0, 256 * sizeof(float), stream);
    hipMemsetAsync(xacc, 0, (size_t)NN * 32 * sizeof(float), stream);

    detect_kernel<<<1, 256, 0, stream>>>((const unsigned int*)x, flag);
    prep_kernel<<<41, 256, 0, stream>>>(
        d_in[10], d_in[12], d_in[14], d_in[16], d_in[18], d_in[20],
        d_in[22], d_in[24],
        d_in[11], d_in[13], d_in[15], d_in[17], d_in[19], d_in[21],
        d_in[23], d_in[25],
        Bfx, Bfy, bx, by, flag);
    convert_kernel<<<4688, 256, 0, stream>>>(x, y, xb, yb, flag);
    // one launch, both sides interleaved: 3125 y-blocks + 1563 x-blocks
    // (+1 guarded spare) via mod-3 mapping.
    fused_both<<<4689, 256, 0, stream>>>(xb, yb, xacc, Bfx, Bfy, bx, by,
                                         deg_g, deg_lg, t_g, tt_g, t_lg, tt_lg,
                                         pm_pd, dst, xmfma, ypre, stats, flag);
    xstats_kernel<<<3125, 256, 0, stream>>>(xmfma, xacc, stats);
    finalize_stats<<<1, 64, 0, stream>>>(stats, d_in[26], d_in[27], d_in[28],
                                         d_in[29], scsh, flag);
    apply_bn<<<9375, 256, 0, stream>>>(xmfma, xacc, ypre, scsh, d_out, flag);
}

// Round 7
// 431.443 us; speedup vs baseline: 1.2579x; 1.0134x over previous
//
#include <hip/hip_runtime.h>

#define NN 100000
#define NE 200000
#define MT (NN + NE)

typedef unsigned short u16;
typedef __attribute__((ext_vector_type(8))) short bf16x8;
typedef __attribute__((ext_vector_type(4))) float f32x4;

__device__ __forceinline__ float bf2f(u16 u) {
    union { unsigned int i; float f; } v; v.i = ((unsigned int)u) << 16; return v.f;
}
__device__ __forceinline__ u16 f2bf(float f) {
    union { unsigned int i; float f; } v; v.f = f;
    unsigned int r = v.i + 0x7fffu + ((v.i >> 16) & 1u);
    return (u16)(r >> 16);
}
__device__ __forceinline__ void unpack2(unsigned int u, float& lo, float& hi) {
    union { unsigned int i; float f; } a, b;
    a.i = u << 16; b.i = u & 0xffff0000u;
    lo = a.f; hi = b.f;
}
__device__ __forceinline__ unsigned int pack2(float a, float b) {
    return (unsigned int)f2bf(a) | ((unsigned int)f2bf(b) << 16);
}
// Dtype-flexible scalar load (R2-R4 proven): f32 flag ? float : bf16.
__device__ __forceinline__ float loadf(const void* p, size_t i, int f32) {
    return f32 ? ((const float*)p)[i] : bf2f(((const u16*)p)[i]);
}
__device__ __forceinline__ void acc8(float a[8], uint4 g) {
    float e0, e1, e2, e3, e4, e5, e6, e7;
    unpack2(g.x, e0, e1); unpack2(g.y, e2, e3);
    unpack2(g.z, e4, e5); unpack2(g.w, e6, e7);
    a[0] += e0; a[1] += e1; a[2] += e2; a[3] += e3;
    a[4] += e4; a[5] += e5; a[6] += e6; a[7] += e7;
}

// Per-block dtype detect (flag=1 => fp32): reads 4KB of x — L2-hit after the
// first block. Result is deterministic and identical across blocks.
__device__ __forceinline__ int detect_local(const unsigned int* x, int* s_cnt) {
    if (threadIdx.x == 0) *s_cnt = 0;
    __syncthreads();
    int bad = 0;
    for (int i = threadIdx.x; i < 1024; i += 256) {
        unsigned int e = (x[i] >> 7) & 0xFF;
        if (e == 0xFF || (e > 0 && (e < 107 || e > 134))) bad++;
    }
    atomicAdd(s_cnt, bad);
    __syncthreads();
    return (*s_cnt > 256) ? 1 : 0;
}

// ONE kernel: dtype detect (local) + B-fragment/bias prep + x/y bf16 convert
// + xacc/stats zeroing. Replaces 4 dispatches + 2 memsets (launch-gap
// overhead was ~200us of the R6 total; kernel-sum only ~210us).
// Bf[b*512 + lane*8 + j] = W_m[k][f], m=b>>1, k=(lane>>4)*8+j,
// f=(b&1)*16+(lane&15)  — the 16x16x32 B-operand layout.
// x side m: [theta_x | theta_deg | theta_r0 | theta_r1]           (8 frags)
// y side m: [gamma_y | gamma_deg | gamma_r0 | gamma_r1 | gamma_x | theta_y]
__global__ __launch_bounds__(256) void prep_convert(
    const void* __restrict__ x, const void* __restrict__ y,
    const void* txw, const void* tdw, const void* tyw,
    const void* gyw, const void* gdw, const void* gxw,
    const void* trw, const void* grw,
    const void* txb, const void* tdb, const void* tyb,
    const void* gyb, const void* gdb, const void* gxb,
    const void* trb, const void* grb,
    u16* __restrict__ xb, u16* __restrict__ yb, float* __restrict__ xacc,
    u16* Bfx, u16* Bfy, float* bx, float* by,
    float* __restrict__ stats, int* flagp)
{
    __shared__ int s_cnt;
    int f32 = detect_local((const unsigned int*)x, &s_cnt);
    size_t t = (size_t)blockIdx.x * 256 + threadIdx.x;
    if (t == 0) *flagp = f32;
    if (t < 256) stats[t] = 0.f;                   // stats(128) + scsh(128)
    if (t < 800000) {                              // zero xacc: NN*32 f32
        float4 z4; z4.x = 0.f; z4.y = 0.f; z4.z = 0.f; z4.w = 0.f;
        ((float4*)xacc)[t] = z4;
    }
    if (t < (size_t)NN * 4) {
        int r = (int)(t >> 2), q = (int)(t & 3);
        uint4 o;
        if (f32) {
            const float4* fp = (const float4*)((const float*)x + (size_t)r * 32 + q * 8);
            float4 v0 = fp[0], v1 = fp[1];
            o.x = pack2(v0.x, v0.y); o.y = pack2(v0.z, v0.w);
            o.z = pack2(v1.x, v1.y); o.w = pack2(v1.z, v1.w);
        } else {
            o = *(const uint4*)((const u16*)x + (size_t)r * 32 + q * 8);
        }
        *(uint4*)(xb + (size_t)r * 32 + q * 8) = o;
    } else if (t < (size_t)MT * 4) {
        size_t t2 = t - (size_t)NN * 4;
        int r = (int)(t2 >> 2), q = (int)(t2 & 3);
        uint4 o;
        if (f32) {
            const float4* fp = (const float4*)((const float*)y + (size_t)r * 32 + q * 8);
            float4 v0 = fp[0], v1 = fp[1];
            o.x = pack2(v0.x, v0.y); o.y = pack2(v0.z, v0.w);
            o.z = pack2(v1.x, v1.y); o.w = pack2(v1.z, v1.w);
        } else {
            o = *(const uint4*)((const u16*)y + (size_t)r * 32 + q * 8);
        }
        *(uint4*)(yb + (size_t)r * 32 + q * 8) = o;
    } else if (t < (size_t)MT * 4 + 10304) {
        int e = (int)(t - (size_t)MT * 4);
        if (e < 4096) {
            int b = e >> 9, lane = (e >> 3) & 63, j = e & 7;
            int m = b >> 1;
            int k = ((lane >> 4) << 3) + j;
            int f = ((b & 1) << 4) + (lane & 15);
            size_t idx = (size_t)k * 32 + f;
            float v = (m == 0) ? loadf(txw, idx, f32) : (m == 1) ? loadf(tdw, idx, f32)
                    : (m == 2) ? loadf(trw, idx, f32) : loadf(trw, 1024 + idx, f32);
            Bfx[e] = f2bf(v);
        } else if (e < 10240) {
            int e2 = e - 4096;
            int b = e2 >> 9, lane = (e2 >> 3) & 63, j = e2 & 7;
            int m = b >> 1;
            int k = ((lane >> 4) << 3) + j;
            int f = ((b & 1) << 4) + (lane & 15);
            size_t idx = (size_t)k * 32 + f;
            float v = (m == 0) ? loadf(gyw, idx, f32) : (m == 1) ? loadf(gdw, idx, f32)
                    : (m == 2) ? loadf(grw, idx, f32) : (m == 3) ? loadf(grw, 1024 + idx, f32)
                    : (m == 4) ? loadf(gxw, idx, f32) : loadf(tyw, idx, f32);
            Bfy[e2] = f2bf(v);
        } else {
            int f = e - 10240;
            if (f < 32) {
                bx[f] = loadf(txb, f, f32) + loadf(tdb, f, f32) + loadf(tyb, f, f32)
                      + loadf(trb, f, f32) + loadf(trb, 32 + f, f32);
            } else {
                f -= 32;
                by[f] = loadf(gyb, f, f32) + loadf(gdb, f, f32) + loadf(gxb, f, f32)
                      + loadf(grb, f, f32) + loadf(grb, 32 + f, f32);
            }
        }
    }
}

// Per-side body of the merged gather+GEMM kernel.
// IS_Y: stats + ypre (bf16, nt) + theta_y scatter into xacc (f32 atomics).
// !IS_Y: atomicAdds the mfma part into xacc directly (xacc pre-zeroed) —
//        removes the separate xmfma buffer (12.8MB write + 2x12.8MB reads).
// Index lists staged with stride 17 (16+1 pad): R4->R5 proved this cuts
// SQ_LDS_BANK_CONFLICT 1.8M -> 300K.
template<int IS_Y>
__device__ __forceinline__ void fused_body(
    const u16* __restrict__ xb, const u16* __restrict__ yb,
    float* xacc,
    const u16* __restrict__ Bf, const float* __restrict__ bias,
    const void* __restrict__ deg,
    const int* __restrict__ tl, const int* __restrict__ ttl,
    const int* __restrict__ pm_pd, const int* __restrict__ dst,
    u16* __restrict__ ypre,
    float* __restrict__ ystats, int f32, int sb,
    int* s_t, int* s_tt, float* s_sum, float* s_sq)
{
    const int M = IS_Y ? NE : NN;
    int row0 = sb * 64;
    if (row0 >= M) return;                       // spare block guard
    if (IS_Y && threadIdx.x < 32) { s_sum[threadIdx.x] = 0.f; s_sq[threadIdx.x] = 0.f; }
    int lim = (M - row0) * 16;
    for (int i = threadIdx.x; i < 1024; i += 256) {
        // nt: index lists are stream-once — don't evict gather-table L2 lines
        int v  = (i < lim) ? __builtin_nontemporal_load(&tl[(size_t)row0 * 16 + i])  : 0;
        int v2 = (i < lim) ? __builtin_nontemporal_load(&ttl[(size_t)row0 * 16 + i]) : 0;
        int si = (i >> 4) * 17 + (i & 15);       // padded stride 17
        s_t[si] = v; s_tt[si] = v2;
    }
    __syncthreads();
    int lane = threadIdx.x & 63, wib = threadIdx.x >> 6;
    int r0 = row0 + wib * 16;
    if (r0 + 16 <= M) {   // full waves only (NN,NE are multiples of 16)
        const u16* tab = IS_Y ? yb : xb;
        int m = lane & 15, q = lane >> 4;
        int gr = r0 + m;
        const int* il  = &s_t[(wib * 16 + m) * 17];
        const int* ill = &s_tt[(wib * 16 + m) * 17];

        bf16x8 selfv = *(const bf16x8*)(tab + (size_t)gr * 32 + q * 8);
        union { u16 s[8]; bf16x8 v; } pm;
        if (IS_Y) {
            int ai = pm_pd[gr];
            pm.v = *(const bf16x8*)(xb + (size_t)ai * 32 + q * 8);
        }

        // 32 raw-row gathers, two-buffer staged: 8-16 loads in flight.
        float aT[8]  = {0.f, 0.f, 0.f, 0.f, 0.f, 0.f, 0.f, 0.f};
        float aTT[8] = {0.f, 0.f, 0.f, 0.f, 0.f, 0.f, 0.f, 0.f};
        uint4 ga[8], gb[8];
#pragma unroll
        for (int j = 0; j < 8; ++j)
            ga[j] = *(const uint4*)(tab + (size_t)il[j] * 32 + q * 8);
#pragma unroll
        for (int j = 0; j < 8; ++j)
            gb[j] = *(const uint4*)(tab + (size_t)il[8 + j] * 32 + q * 8);
#pragma unroll
        for (int j = 0; j < 8; ++j) acc8(aT, ga[j]);
#pragma unroll
        for (int j = 0; j < 8; ++j)
            ga[j] = *(const uint4*)(tab + (size_t)ill[j] * 32 + q * 8);
#pragma unroll
        for (int j = 0; j < 8; ++j) acc8(aT, gb[j]);
#pragma unroll
        for (int j = 0; j < 8; ++j)
            gb[j] = *(const uint4*)(tab + (size_t)ill[8 + j] * 32 + q * 8);
#pragma unroll
        for (int j = 0; j < 8; ++j) acc8(aTT, ga[j]);
#pragma unroll
        for (int j = 0; j < 8; ++j) acc8(aTT, gb[j]);

        union { u16 s[8]; bf16x8 v; } ft, ftt;
#pragma unroll
        for (int j = 0; j < 8; ++j) { ft.s[j] = f2bf(aT[j]); ftt.s[j] = f2bf(aTT[j]); }

        const u16* bp = Bf + lane * 8;
#define BFR(b) (*(const bf16x8*)(bp + (b) * 512))
        f32x4 z = {0.f, 0.f, 0.f, 0.f};
        f32x4 a0, a1, d0, d1, c0 = z, c1 = z;
        a0 = __builtin_amdgcn_mfma_f32_16x16x32_bf16(selfv, BFR(0), z, 0, 0, 0);
        a1 = __builtin_amdgcn_mfma_f32_16x16x32_bf16(selfv, BFR(1), z, 0, 0, 0);
        d0 = __builtin_amdgcn_mfma_f32_16x16x32_bf16(selfv, BFR(2), z, 0, 0, 0);
        d1 = __builtin_amdgcn_mfma_f32_16x16x32_bf16(selfv, BFR(3), z, 0, 0, 0);
        a0 = __builtin_amdgcn_mfma_f32_16x16x32_bf16(ft.v,  BFR(4), a0, 0, 0, 0);
        a1 = __builtin_amdgcn_mfma_f32_16x16x32_bf16(ft.v,  BFR(5), a1, 0, 0, 0);
        a0 = __builtin_amdgcn_mfma_f32_16x16x32_bf16(ftt.v, BFR(6), a0, 0, 0, 0);
        a1 = __builtin_amdgcn_mfma_f32_16x16x32_bf16(ftt.v, BFR(7), a1, 0, 0, 0);
        if (IS_Y) {
            a0 = __builtin_amdgcn_mfma_f32_16x16x32_bf16(pm.v,  BFR(8),  a0, 0, 0, 0);
            a1 = __builtin_amdgcn_mfma_f32_16x16x32_bf16(pm.v,  BFR(9),  a1, 0, 0, 0);
            c0 = __builtin_amdgcn_mfma_f32_16x16x32_bf16(selfv, BFR(10), z, 0, 0, 0);
            c1 = __builtin_amdgcn_mfma_f32_16x16x32_bf16(selfv, BFR(11), z, 0, 0, 0);
        }
#undef BFR

        // D layout: col = lane&15 (=m), row = q*4 + i
        int n = m;
        int rowb = r0 + q * 4;
        float bl_ = bias[n], bh_ = bias[16 + n];
        float s0 = 0.f, q0 = 0.f, s1 = 0.f, q1 = 0.f;
#pragma unroll
        for (int i = 0; i < 4; ++i) {
            float dgi = loadf(deg, rowb + i, f32);
            size_t ro = (size_t)(rowb + i) * 32;
            float lo = a0[i] + dgi * d0[i] + bl_;
            float hi = a1[i] + dgi * d1[i] + bh_;
            if (!IS_Y) {
                // accumulate mfma part into xacc (y-scatter adds the rest);
                // xstats/apply_bn read the completed sum after this kernel.
                atomicAdd(&xacc[ro + n],      lo);
                atomicAdd(&xacc[ro + 16 + n], hi);
            } else {
                hi = fmaxf(hi, 0.f);
                __builtin_nontemporal_store(f2bf(lo), &ypre[ro + n]);
                __builtin_nontemporal_store(f2bf(hi), &ypre[ro + 16 + n]);
                int d = dst[rowb + i];
                float* p = xacc + (size_t)d * 32;
                atomicAdd(p + n,      c0[i]);
                atomicAdd(p + 16 + n, c1[i]);
                s0 += lo; q0 += lo * lo;
                s1 += hi; q1 += hi * hi;
            }
        }
        if (IS_Y) {
            // cross-lane pre-reduce over the 4 lanes sharing n (lane, lane^16,
            // lane^32) before the shared atomic: 1024 -> 256 LDS atomics/block
            s0 += __shfl_xor(s0, 16); s0 += __shfl_xor(s0, 32);
            q0 += __shfl_xor(q0, 16); q0 += __shfl_xor(q0, 32);
            s1 += __shfl_xor(s1, 16); s1 += __shfl_xor(s1, 32);
            q1 += __shfl_xor(q1, 16); q1 += __shfl_xor(q1, 32);
            if (lane < 16) {
                atomicAdd(&s_sum[n], s0);      atomicAdd(&s_sq[n], q0);
                atomicAdd(&s_sum[16 + n], s1); atomicAdd(&s_sq[16 + n], q1);
            }
        }
    }
    if (IS_Y) {
        __syncthreads();
        if (threadIdx.x < 32) {
            atomicAdd(&ystats[threadIdx.x], s_sum[threadIdx.x]);
            atomicAdd(&ystats[32 + threadIdx.x], s_sq[threadIdx.x]);
        }
    }
}

// Merged launch: mod-3 block interleave (2 y-blocks : 1 x-block) keeps both
// sides' traffic mixed on the TCC-miss path for the whole kernel.
// (256,3): R5 proved (256,4) forces VGPR 84->64 and spills the 16 staging
// uint4s to scratch (+289MB write, +180MB fetch, 181->280us). Keep 3.
__global__ __launch_bounds__(256, 3) void fused_both(
    const u16* __restrict__ xb, const u16* __restrict__ yb, float* xacc,
    const u16* __restrict__ Bfx, const u16* __restrict__ Bfy,
    const float* __restrict__ bx, const float* __restrict__ by,
    const void* __restrict__ deg_g, const void* __restrict__ deg_lg,
    const int* __restrict__ t_g, const int* __restrict__ tt_g,
    const int* __restrict__ t_lg, const int* __restrict__ tt_lg,
    const int* __restrict__ pm_pd, const int* __restrict__ dst,
    u16* __restrict__ ypre,
    float* __restrict__ stats, const int* __restrict__ flagp)
{
    __shared__ int s_t[1088];        // 64 rows x (16+1 pad)
    __shared__ int s_tt[1088];
    __shared__ float s_sum[32];
    __shared__ float s_sq[32];
    int f32 = *flagp;
    int bid = blockIdx.x;
    int s = bid % 3;
    if (s == 2) {
        fused_body<0>(xb, yb, xacc, Bfx, bx, deg_g, t_g, tt_g, pm_pd, dst,
                      ypre, stats, f32, bid / 3,
                      s_t, s_tt, s_sum, s_sq);
    } else {
        fused_body<1>(xb, yb, xacc, Bfy, by, deg_lg, t_lg, tt_lg, pm_pd, dst,
                      ypre, stats + 64, f32, (bid / 3) * 2 + s,
                      s_t, s_tt, s_sum, s_sq);
    }
}

// x stats only: reads completed xacc (= mfma part + theta_y scatter), applies
// ReLU to upper half in-register, accumulates BN stats. No store.
__global__ __launch_bounds__(256) void xstats_kernel(
    const float* __restrict__ xacc, float* __restrict__ stats)
{
    __shared__ float s_sum[32];
    __shared__ float s_sq[32];
    if (threadIdx.x < 32) { s_sum[threadIdx.x] = 0.f; s_sq[threadIdx.x] = 0.f; }
    __syncthreads();
    int tid = blockIdx.x * 256 + threadIdx.x;    // NN*8 threads, 4 elems each
    int fq = (tid & 7) * 4;
    float4 b = ((const float4*)xacc)[tid];
    float sv[4], qv[4];
    sv[0] = b.x; sv[1] = b.y; sv[2] = b.z; sv[3] = b.w;
    if (fq >= 16) {
#pragma unroll
        for (int i = 0; i < 4; ++i) sv[i] = fmaxf(sv[i], 0.f);
    }
#pragma unroll
    for (int i = 0; i < 4; ++i) qv[i] = sv[i] * sv[i];
    // cross-lane pre-reduce over the 8 lanes sharing fq (xor 8,16,32)
#pragma unroll
    for (int off = 8; off < 64; off <<= 1) {
#pragma unroll
        for (int i = 0; i < 4; ++i) {
            sv[i] += __shfl_xor(sv[i], off);
            qv[i] += __shfl_xor(qv[i], off);
        }
    }
    int lane = threadIdx.x & 63;
    if (lane < 8) {
        int f0 = lane * 4;
#pragma unroll
        for (int i = 0; i < 4; ++i) {
            atomicAdd(&s_sum[f0 + i], sv[i]);
            atomicAdd(&s_sq[f0 + i], qv[i]);
        }
    }
    __syncthreads();
    if (threadIdx.x < 32) {
        atomicAdd(&stats[threadIdx.x], s_sum[threadIdx.x]);
        atomicAdd(&stats[32 + threadIdx.x], s_sq[threadIdx.x]);
    }
}

// BN apply with the scale/shift finalize inlined (per-block recompute in
// shared: 64 threads x 2 rsqrt — removes the 1-block finalize dispatch).
__global__ __launch_bounds__(256) void apply_bn(
    const float* __restrict__ xacc, const u16* __restrict__ ypre,
    const float* __restrict__ stats,
    const void* __restrict__ bnxw, const void* __restrict__ bnxb,
    const void* __restrict__ bnyw, const void* __restrict__ bnyb,
    void* __restrict__ out, const int* __restrict__ flagp)
{
    __shared__ float s_sc[128];
    int f32 = *flagp;
    if (threadIdx.x < 64) {
        int f = threadIdx.x;
        if (f < 32) {
            float m = stats[f] / (float)NN;
            float var = stats[32 + f] / (float)NN - m * m;
            float inv = rsqrtf(var + 1e-5f);
            float sc = loadf(bnxw, f, f32) * inv;
            s_sc[f] = sc; s_sc[32 + f] = loadf(bnxb, f, f32) - m * sc;
        } else {
            int g = f - 32;
            float m = stats[64 + g] / (float)NE;
            float var = stats[96 + g] / (float)NE - m * m;
            float inv = rsqrtf(var + 1e-5f);
            float sc = loadf(bnyw, g, f32) * inv;
            s_sc[64 + g] = sc; s_sc[96 + g] = loadf(bnyb, g, f32) - m * sc;
        }
    }
    __syncthreads();
    int tid = blockIdx.x * 256 + threadIdx.x;   // MT*8 threads, 4 elems each
    if (tid >= MT * 8) return;
    int fq = (tid & 7) * 4;
    const float* sc;
    float4 v;
    if (tid < NN * 8) {
        v = ((const float4*)xacc)[tid];
        if (fq >= 16) {
            v.x = fmaxf(v.x, 0.f); v.y = fmaxf(v.y, 0.f);
            v.z = fmaxf(v.z, 0.f); v.w = fmaxf(v.w, 0.f);
        }
        sc = s_sc;
    } else {
        size_t off = (size_t)tid * 4 - (size_t)NN * 32;
        ushort4 u = *(const ushort4*)(ypre + off);
        v.x = bf2f(u.x); v.y = bf2f(u.y); v.z = bf2f(u.z); v.w = bf2f(u.w);
        sc = s_sc + 64;
    }
    float o0 = v.x * sc[fq + 0] + sc[32 + fq + 0];
    float o1 = v.y * sc[fq + 1] + sc[32 + fq + 1];
    float o2 = v.z * sc[fq + 2] + sc[32 + fq + 2];
    float o3 = v.w * sc[fq + 3] + sc[32 + fq + 3];
    if (f32) {
        float4 o; o.x = o0; o.y = o1; o.z = o2; o.w = o3;
        ((float4*)out)[tid] = o;
    } else {
        ushort4 o; o.x = f2bf(o0); o.y = f2bf(o1); o.z = f2bf(o2); o.w = f2bf(o3);
        ((ushort4*)out)[tid] = o;
    }
}

extern "C" void kernel_launch(void* const* d_in, const int* in_sizes, int n_in,
                              void* d_out, int out_size, void* d_ws, size_t ws_size,
                              hipStream_t stream)
{
    const void* x      = d_in[0];
    const void* y      = d_in[1];
    const void* deg_g  = d_in[2];
    const void* deg_lg = d_in[3];
    const int* t_g   = (const int*)d_in[4];
    const int* tt_g  = (const int*)d_in[5];
    const int* t_lg  = (const int*)d_in[6];
    const int* tt_lg = (const int*)d_in[7];
    const int* dst   = (const int*)d_in[8];
    const int* pm_pd = (const int*)d_in[9];

    char* ws = (char*)d_ws;
    int*   flag = (int*)ws;                     // 4 B
    u16* Bfx   = (u16*)(ws + 256);              // 4096 u16 = 8 KB
    u16* Bfy   = Bfx + 4096;                    // 6144 u16 = 12 KB
    float* bx  = (float*)(ws + 24576);          // 32 f32
    float* by  = bx + 32;
    float* stats = by + 32;                     // 128 f32 (+128 scsh slack)
    u16* xb    = (u16*)(ws + 65536);            // NN*32 bf16 = 6.4 MB
    u16* yb    = xb + (size_t)NN * 32;          // NE*32 bf16 = 12.8 MB
    float* xacc = (float*)(yb + (size_t)NE * 32); // NN*32 f32 = 12.8 MB
    u16* ypre  = (u16*)(xacc + (size_t)NN * 32);  // NE*32 bf16 = 12.8 MB
    // total ≈ 64 KB + 44.8 MB

    // 4 dispatches total (was 9 incl. 2 memsets): launch-gap overhead was the
    // dominant non-kernel cost in R4-R6 (total-sum ≈ 200us over 9 gaps).
    prep_convert<<<4728, 256, 0, stream>>>(
        x, y,
        d_in[10], d_in[12], d_in[14], d_in[16], d_in[18], d_in[20],
        d_in[22], d_in[24],
        d_in[11], d_in[13], d_in[15], d_in[17], d_in[19], d_in[21],
        d_in[23], d_in[25],
        xb, yb, xacc, Bfx, Bfy, bx, by, stats, flag);
    fused_both<<<4689, 256, 0, stream>>>(xb, yb, xacc, Bfx, Bfy, bx, by,
                                         deg_g, deg_lg, t_g, tt_g, t_lg, tt_lg,
                                         pm_pd, dst, ypre, stats, flag);
    xstats_kernel<<<3125, 256, 0, stream>>>(xacc, stats);
    apply_bn<<<9375, 256, 0, stream>>>(xacc, ypre, stats,
                                       d_in[26], d_in[27], d_in[28], d_in[29],
                                       d_out, flag);
}